// Round 13
// baseline (278.930 us; speedup 1.0000x reference)
//
#include <hip/hip_runtime.h>
#include <math.h>

#define VN 16
#define TN 2048
#define NROWS (VN*TN)   // 32768
#define DIN 64
#define HID 128
#define DKD 48
#define KNB 33
#define BR 32
#define BR16 16
#define KPAD 52
#define XPAD 36
#define HPAD 132   // row-major s_h row length (128+4)

// ---------------- Threefry-2x32, key = (0, 42) ----------------
__device__ __forceinline__ unsigned rotl32(unsigned x, int d){ return (x<<d)|(x>>(32-d)); }

__device__ __forceinline__ void tf2x32(unsigned c0, unsigned c1, unsigned& y0, unsigned& y1){
  const unsigned k0 = 0u, k1 = 42u;
  const unsigned k2 = k0 ^ k1 ^ 0x1BD11BDAu;
  unsigned x0 = c0, x1 = c1;
  x0 += k0; x1 += k1;
#define TF_R(r) { x0 += x1; x1 = rotl32(x1,(r)); x1 ^= x0; }
  TF_R(13) TF_R(15) TF_R(26) TF_R(6)   x0 += k1; x1 += k2 + 1u;
  TF_R(17) TF_R(29) TF_R(16) TF_R(24)  x0 += k2; x1 += k0 + 2u;
  TF_R(13) TF_R(15) TF_R(26) TF_R(6)   x0 += k0; x1 += k1 + 3u;
  TF_R(17) TF_R(29) TF_R(16) TF_R(24)  x0 += k1; x1 += k2 + 4u;
  TF_R(13) TF_R(15) TF_R(26) TF_R(6)   x0 += k2; x1 += k0 + 5u;
#undef TF_R
  y0 = x0; y1 = x1;
}

// exact f64 md for element n (partitionable 64-bit threefry stream, np-ref semantics)
__device__ __forceinline__ double md64_of(const float* __restrict__ max_depth, int n){
  unsigned y0, y1;
  tf2x32(0u, (unsigned)n, y0, y1);
  unsigned long long bits = (((unsigned long long)y0) << 32) | (unsigned long long)y1;
  unsigned long long fb = (bits >> 12) | 0x3FF0000000000000ull;   // [1,2)
  double f; __builtin_memcpy(&f, &fb, 8);
  f -= 1.0;
  return (double)max_depth[n] + f * (1.0/8192.0);
}

// ---------------- prep: md64 + metadata transposes [V][T] -> [T][16] ----------------
__global__ __launch_bounds__(256) void prep_kernel(const float* __restrict__ max_depth,
    const int* __restrict__ pv, const int* __restrict__ nv, const int* __restrict__ ind,
    const float* __restrict__ pm, const float* __restrict__ nm,
    double* __restrict__ mdT, int* __restrict__ pvT, int* __restrict__ nvT,
    int* __restrict__ idxT, float* __restrict__ pmT, float* __restrict__ nmT)
{
  int n = blockIdx.x*256 + threadIdx.x;
  int v = n >> 11, t = n & 2047;
  int o = t*VN + v;
  mdT[o]  = md64_of(max_depth, n);
  pvT[o]  = pv[n];
  nvT[o]  = nv[n];
  idxT[o] = ind[n];
  pmT[o]  = pm[n];
  nmT[o]  = nm[n];
}

// ---------------- prep: W2 transposes [128][48] -> [48][128], 3 matrices ----------------
__global__ __launch_bounds__(256) void prep_w2t(const float* __restrict__ Wq2,
    const float* __restrict__ Wk2, const float* __restrict__ Wv2, float* __restrict__ w2t)
{
  int idx = blockIdx.x*256 + threadIdx.x;      // [0, 3*6144)
  int mm = idx / (HID*DKD);
  int e  = idx - mm*(HID*DKD);
  int o = e >> 7, i = e & 127;                 // output row o, input col i
  const float* src = (mm==0) ? Wq2 : (mm==1 ? Wk2 : Wv2);
  w2t[idx] = src[i*DKD + o];                   // w2t[mm][o][i]
}

// ---------------- q/k/v MLPs: grid-split mm, vectorized layer2 via W2T ----------------
__global__ __launch_bounds__(256) void qkv_kernel(const float* __restrict__ enc,
    const float* __restrict__ Wq1, const float* __restrict__ bq1, const float* __restrict__ bq2,
    const float* __restrict__ Wk1, const float* __restrict__ bk1, const float* __restrict__ bk2,
    const float* __restrict__ Wv1, const float* __restrict__ bv1, const float* __restrict__ bv2,
    const float* __restrict__ w2t,
    float* __restrict__ qo, float* __restrict__ ko, float* __restrict__ vo)
{
  __shared__ __align__(16) float s_x[DIN][XPAD];     // 9.2 KB
  __shared__ __align__(16) float s_h[BR][HPAD];      // 16.9 KB row-major
  int tid = threadIdx.x;
  int mm   = blockIdx.x >> 10;            // 1024 blocks per matrix
  int base = (blockIdx.x & 1023) * BR;

  const float *W1, *b1, *b2; float* outp;
  if (mm == 0){ W1=Wq1; b1=bq1; b2=bq2; outp=qo; }
  else if (mm == 1){ W1=Wk1; b1=bk1; b2=bk2; outp=ko; }
  else        { W1=Wv1; b1=bv1; b2=bv2; outp=vo; }
  const float* __restrict__ W2T = w2t + mm*(HID*DKD);

  for (int idx = tid; idx < BR*DIN; idx += 256){
    int r = idx >> 6, c = idx & 63;
    s_x[c][r] = enc[(size_t)(base+r)*DIN + c];
  }
  __syncthreads();

  // layer 1: 4 rows x 4 units per thread; per i: 1 LDS float4 + 1 global float4 -> 16 FMA
  const int u0 = (tid & 31) * 4;
  const int r0 = (tid >> 5) * 4;
  {
    float acc[4][4];
    float c0=b1[u0], c1=b1[u0+1], c2=b1[u0+2], c3=b1[u0+3];
    #pragma unroll
    for (int r=0;r<4;r++){ acc[r][0]=c0; acc[r][1]=c1; acc[r][2]=c2; acc[r][3]=c3; }
    #pragma unroll 8
    for (int i=0;i<DIN;i++){
      const float4 xv = *reinterpret_cast<const float4*>(&s_x[i][r0]);
      const float4 wv = *reinterpret_cast<const float4*>(&W1[i*HID + u0]);
      float xd[4] = {xv.x, xv.y, xv.z, xv.w};
      float wd[4] = {wv.x, wv.y, wv.z, wv.w};
      #pragma unroll
      for (int r=0;r<4;r++)
        #pragma unroll
        for (int j=0;j<4;j++)
          acc[r][j] = fmaf(xd[r], wd[j], acc[r][j]);
    }
    // row-major write: 4 x b128, lanes consecutive in u0 -> conflict-free
    #pragma unroll
    for (int r=0;r<4;r++){
      float4 hv;
      hv.x=fmaxf(acc[r][0],0.0f); hv.y=fmaxf(acc[r][1],0.0f);
      hv.z=fmaxf(acc[r][2],0.0f); hv.w=fmaxf(acc[r][3],0.0f);
      *reinterpret_cast<float4*>(&s_h[r0+r][u0]) = hv;
    }
  }
  __syncthreads();

  // layer 2: thread = (2 rows, outs {o0, o0+16, o0+32}); per i4: 2 LDS b128 + 3 global b128 -> 24 FMA
  const int o0 = tid & 15;
  const int rp = (tid >> 4) * 2;
  {
    float a[2][3];
    a[0][0]=b2[o0]; a[0][1]=b2[o0+16]; a[0][2]=b2[o0+32];
    a[1][0]=a[0][0]; a[1][1]=a[0][1]; a[1][2]=a[0][2];
    const float* __restrict__ w2r0 = W2T + (size_t)o0*HID;
    const float* __restrict__ w2r1 = W2T + (size_t)(o0+16)*HID;
    const float* __restrict__ w2r2 = W2T + (size_t)(o0+32)*HID;
    #pragma unroll 4
    for (int i4=0;i4<HID/4;i4++){
      const int ib = i4*4;
      const float4 h0 = *reinterpret_cast<const float4*>(&s_h[rp  ][ib]);
      const float4 h1 = *reinterpret_cast<const float4*>(&s_h[rp+1][ib]);
      const float4 w0 = *reinterpret_cast<const float4*>(&w2r0[ib]);
      const float4 w1 = *reinterpret_cast<const float4*>(&w2r1[ib]);
      const float4 w2 = *reinterpret_cast<const float4*>(&w2r2[ib]);
      a[0][0]=fmaf(h0.x,w0.x,a[0][0]); a[0][0]=fmaf(h0.y,w0.y,a[0][0]);
      a[0][0]=fmaf(h0.z,w0.z,a[0][0]); a[0][0]=fmaf(h0.w,w0.w,a[0][0]);
      a[0][1]=fmaf(h0.x,w1.x,a[0][1]); a[0][1]=fmaf(h0.y,w1.y,a[0][1]);
      a[0][1]=fmaf(h0.z,w1.z,a[0][1]); a[0][1]=fmaf(h0.w,w1.w,a[0][1]);
      a[0][2]=fmaf(h0.x,w2.x,a[0][2]); a[0][2]=fmaf(h0.y,w2.y,a[0][2]);
      a[0][2]=fmaf(h0.z,w2.z,a[0][2]); a[0][2]=fmaf(h0.w,w2.w,a[0][2]);
      a[1][0]=fmaf(h1.x,w0.x,a[1][0]); a[1][0]=fmaf(h1.y,w0.y,a[1][0]);
      a[1][0]=fmaf(h1.z,w0.z,a[1][0]); a[1][0]=fmaf(h1.w,w0.w,a[1][0]);
      a[1][1]=fmaf(h1.x,w1.x,a[1][1]); a[1][1]=fmaf(h1.y,w1.y,a[1][1]);
      a[1][1]=fmaf(h1.z,w1.z,a[1][1]); a[1][1]=fmaf(h1.w,w1.w,a[1][1]);
      a[1][2]=fmaf(h1.x,w2.x,a[1][2]); a[1][2]=fmaf(h1.y,w2.y,a[1][2]);
      a[1][2]=fmaf(h1.z,w2.z,a[1][2]); a[1][2]=fmaf(h1.w,w2.w,a[1][2]);
    }
    float* op0 = outp + (size_t)(base+rp)*DKD;
    float* op1 = op0 + DKD;
    op0[o0]=a[0][0]; op0[o0+16]=a[0][1]; op0[o0+32]=a[0][2];
    op1[o0]=a[1][0]; op1[o0+16]=a[1][1]; op1[o0+32]=a[1][2];
  }
}

// ---------------- attention: direct K gather, LDS role, transposed metadata ----------------
__global__ __launch_bounds__(256) void attn_kernel(const float* __restrict__ qv,
    const float* __restrict__ kv, const float* __restrict__ vv,
    const float* __restrict__ role_emb, const double* __restrict__ mdT,
    const int* __restrict__ pvT, const int* __restrict__ nvT, const int* __restrict__ idxT,
    const float* __restrict__ pmT, const float* __restrict__ nmT,
    const int* __restrict__ window_indices, const float* __restrict__ window_mask,
    float* __restrict__ ctx_out)
{
  __shared__ __align__(16) float s_role[KNB][KPAD];   // 6.9 KB (block-uniform)
  __shared__ __align__(16) float s_q[4][DKD];
  __shared__ float s_p[4][KNB];
  __shared__ int   s_idx[4][KNB];
  int tid  = threadIdx.x;          // 256
  int wid  = tid >> 6;
  int lane = tid & 63;
  int n = blockIdx.x*4 + wid;
  int vrow = n >> 11;              // all 4 rows in block share vrow
  int t    = n & 2047;

  if (lane < DKD) s_q[wid][lane] = qv[(size_t)n*DKD + lane];

  // stage role rows (block-uniform: depend only on vrow)
  for (int idx = tid; idx < KNB*DKD; idx += 256){
    int j = idx / DKD, d = idx - j*DKD;
    int role = (j < 16) ? (vrow<<4)+j : ((j < 32) ? 256+(vrow<<4)+(j-16) : 512+vrow);
    s_role[j][d] = role_emb[(size_t)role*DKD + d];
  }
  __syncthreads();

  float sc = -INFINITY;
  if (lane < KNB){
    int gidx; bool valid;
    if (lane < 16){
      int o = t*VN + lane;
      gidx  = pvT[o];
      valid = (pmT[o] == 0.0f);
    } else if (lane < 32){
      int v2 = lane - 16, o = t*VN + v2;
      bool comp = mdT[t*VN + vrow] > mdT[o];   // exact f64 (np-ref semantics)
      gidx  = comp ? idxT[o] : nvT[o];
      valid = comp || (nmT[o] == 0.0f);
    } else {
      gidx  = window_indices[n];
      valid = (window_mask[n] == 0.0f);
    }
    s_idx[wid][lane] = gidx;
    // direct per-lane K gather: 3 independent float4 loads (HW-pipelined)
    const float4* kp = reinterpret_cast<const float4*>(kv + (size_t)gidx*DKD);
    float acc = 0.0f;
    #pragma unroll
    for (int d4 = 0; d4 < DKD/4; d4++){
      const float4 qq = *reinterpret_cast<const float4*>(&s_q[wid][4*d4]);
      const float4 rr = *reinterpret_cast<const float4*>(&s_role[lane][4*d4]);
      const float4 kk = kp[d4];
      acc = fmaf(qq.x, kk.x + rr.x, acc);
      acc = fmaf(qq.y, kk.y + rr.y, acc);
      acc = fmaf(qq.z, kk.z + rr.z, acc);
      acc = fmaf(qq.w, kk.w + rr.w, acc);
    }
    sc = acc / 6.928203230275509f;   // sqrt(48)
    if (!valid) sc = -1e9f;
  }
  float mx = sc;
  #pragma unroll
  for (int o=32;o>0;o>>=1) mx = fmaxf(mx, __shfl_xor(mx, o, 64));
  float e = (lane < KNB) ? expf(sc - mx) : 0.0f;
  float ssum = e;
  #pragma unroll
  for (int o=32;o>0;o>>=1) ssum += __shfl_xor(ssum, o, 64);
  if (lane < KNB) s_p[wid][lane] = e / ssum;

  if (lane < DKD){
    float c = 0.0f;
    #pragma unroll 8
    for (int j=0;j<KNB;j++)
      c = fmaf(s_p[wid][j], vv[(size_t)s_idx[wid][j]*DKD + lane], c);
    ctx_out[(size_t)n*DKD + lane] = c;
  }
}

// ---------------- heads: 16 rows/block, hidden in registers, shuffle-reduced layer2 ----------------
__device__ __forceinline__ double nlogp_d(double x, double mu, double ls){
  double sp = fmax(ls, 0.0) + log1p(exp(-fabs(ls)));
  double s = sp + 1e-3;
  double z = (x - mu) / s;
  return 0.5*z*z + log(s) + 0.9189385332046727417803297; // 0.5*log(2*pi)
}

__global__ __launch_bounds__(256) void heads_kernel(const float* __restrict__ enc,
    const float* __restrict__ ctx, const float* __restrict__ uu,
    const float* __restrict__ Wd1, const float* __restrict__ bd1,
    const float* __restrict__ Wd2, const float* __restrict__ bd2,
    const float* __restrict__ Wm1, const float* __restrict__ bm1,
    const float* __restrict__ Wm2, const float* __restrict__ bm2,
    float* __restrict__ out)
{
  __shared__ float s_x[DIN+DKD][BR16+2];   // [112][18] 8.06 KB
  __shared__ float s_o[BR16][4];
  int tid = threadIdx.x;     // 256
  int base = blockIdx.x * BR16;

  for (int idx = tid; idx < BR16*DIN; idx += 256){
    int r = idx >> 6, c = idx & 63;
    s_x[c][r] = enc[(size_t)(base+r)*DIN + c];
  }
  for (int idx = tid; idx < BR16*DKD; idx += 256){
    int r = idx / DKD, c = idx - r*DKD;
    s_x[DIN + c][r] = ctx[(size_t)(base+r)*DKD + c];
  }
  __syncthreads();

  const int u0 = (tid & 31) * 4;
  const int r0 = (tid >> 5) * 2;

  float pd[2][2] = {{0.f,0.f},{0.f,0.f}};
  float pm[2][2] = {{0.f,0.f},{0.f,0.f}};

  // dp: hidden 112->128 into regs, partial dot vs Wd2
  {
    float acc[2][4];
    float c0=bd1[u0], c1=bd1[u0+1], c2=bd1[u0+2], c3=bd1[u0+3];
    acc[0][0]=c0; acc[0][1]=c1; acc[0][2]=c2; acc[0][3]=c3;
    acc[1][0]=c0; acc[1][1]=c1; acc[1][2]=c2; acc[1][3]=c3;
    #pragma unroll 8
    for (int i=0;i<DIN+DKD;i++){
      const float2 xv = *reinterpret_cast<const float2*>(&s_x[i][r0]);
      const float4 wv = *reinterpret_cast<const float4*>(&Wd1[i*HID + u0]);
      acc[0][0]=fmaf(xv.x,wv.x,acc[0][0]); acc[0][1]=fmaf(xv.x,wv.y,acc[0][1]);
      acc[0][2]=fmaf(xv.x,wv.z,acc[0][2]); acc[0][3]=fmaf(xv.x,wv.w,acc[0][3]);
      acc[1][0]=fmaf(xv.y,wv.x,acc[1][0]); acc[1][1]=fmaf(xv.y,wv.y,acc[1][1]);
      acc[1][2]=fmaf(xv.y,wv.z,acc[1][2]); acc[1][3]=fmaf(xv.y,wv.w,acc[1][3]);
    }
    #pragma unroll
    for (int j=0;j<4;j++){
      const float2 w2 = *reinterpret_cast<const float2*>(&Wd2[(u0+j)*2]);
      float h0 = fmaxf(acc[0][j],0.0f), h1 = fmaxf(acc[1][j],0.0f);
      pd[0][0]=fmaf(h0,w2.x,pd[0][0]); pd[0][1]=fmaf(h0,w2.y,pd[0][1]);
      pd[1][0]=fmaf(h1,w2.x,pd[1][0]); pd[1][1]=fmaf(h1,w2.y,pd[1][1]);
    }
  }
  // mp: hidden 64->128 into regs, partial dot vs Wm2
  {
    float acc[2][4];
    float c0=bm1[u0], c1=bm1[u0+1], c2=bm1[u0+2], c3=bm1[u0+3];
    acc[0][0]=c0; acc[0][1]=c1; acc[0][2]=c2; acc[0][3]=c3;
    acc[1][0]=c0; acc[1][1]=c1; acc[1][2]=c2; acc[1][3]=c3;
    #pragma unroll 8
    for (int i=0;i<DIN;i++){
      const float2 xv = *reinterpret_cast<const float2*>(&s_x[i][r0]);
      const float4 wv = *reinterpret_cast<const float4*>(&Wm1[i*HID + u0]);
      acc[0][0]=fmaf(xv.x,wv.x,acc[0][0]); acc[0][1]=fmaf(xv.x,wv.y,acc[0][1]);
      acc[0][2]=fmaf(xv.x,wv.z,acc[0][2]); acc[0][3]=fmaf(xv.x,wv.w,acc[0][3]);
      acc[1][0]=fmaf(xv.y,wv.x,acc[1][0]); acc[1][1]=fmaf(xv.y,wv.y,acc[1][1]);
      acc[1][2]=fmaf(xv.y,wv.z,acc[1][2]); acc[1][3]=fmaf(xv.y,wv.w,acc[1][3]);
    }
    #pragma unroll
    for (int j=0;j<4;j++){
      const float2 w2 = *reinterpret_cast<const float2*>(&Wm2[(u0+j)*2]);
      float h0 = fmaxf(acc[0][j],0.0f), h1 = fmaxf(acc[1][j],0.0f);
      pm[0][0]=fmaf(h0,w2.x,pm[0][0]); pm[0][1]=fmaf(h0,w2.y,pm[0][1]);
      pm[1][0]=fmaf(h1,w2.x,pm[1][0]); pm[1][1]=fmaf(h1,w2.y,pm[1][1]);
    }
  }
  // tree-reduce the 8 partials over the 32 lanes sharing (r0, r0+1)
  #pragma unroll
  for (int o=1;o<=16;o<<=1){
    pd[0][0]+=__shfl_xor(pd[0][0],o,64); pd[0][1]+=__shfl_xor(pd[0][1],o,64);
    pd[1][0]+=__shfl_xor(pd[1][0],o,64); pd[1][1]+=__shfl_xor(pd[1][1],o,64);
    pm[0][0]+=__shfl_xor(pm[0][0],o,64); pm[0][1]+=__shfl_xor(pm[0][1],o,64);
    pm[1][0]+=__shfl_xor(pm[1][0],o,64); pm[1][1]+=__shfl_xor(pm[1][1],o,64);
  }
  if ((tid & 31) == 0){
    #pragma unroll
    for (int rr=0;rr<2;rr++){
      s_o[r0+rr][0] = pd[rr][0] + bd2[0];
      s_o[r0+rr][1] = pd[rr][1] + bd2[1];
      s_o[r0+rr][2] = pm[rr][0] + bm2[0];
      s_o[r0+rr][3] = pm[rr][1] + bm2[1];
    }
  }
  __syncthreads();

  if (tid < BR16){
    double x = (double)uu[base + tid];
    out[base + tid] = (float)(nlogp_d(x, (double)s_o[tid][0], (double)s_o[tid][1]) +
                              nlogp_d(x, (double)s_o[tid][2], (double)s_o[tid][3]));
  }
}

extern "C" void kernel_launch(void* const* d_in, const int* in_sizes, int n_in,
                              void* d_out, int out_size, void* d_ws, size_t ws_size,
                              hipStream_t stream) {
  const float* encoded = (const float*)d_in[0];
  const float* u       = (const float*)d_in[1];
  const float* Wq1 = (const float*)d_in[2];  const float* bq1 = (const float*)d_in[3];
  const float* Wq2 = (const float*)d_in[4];  const float* bq2 = (const float*)d_in[5];
  const float* Wk1 = (const float*)d_in[6];  const float* bk1 = (const float*)d_in[7];
  const float* Wk2 = (const float*)d_in[8];  const float* bk2 = (const float*)d_in[9];
  const float* Wv1 = (const float*)d_in[10]; const float* bv1 = (const float*)d_in[11];
  const float* Wv2 = (const float*)d_in[12]; const float* bv2 = (const float*)d_in[13];
  const float* role_emb = (const float*)d_in[14];
  const float* Wd1 = (const float*)d_in[15]; const float* bd1 = (const float*)d_in[16];
  const float* Wd2 = (const float*)d_in[17]; const float* bd2 = (const float*)d_in[18];
  const float* Wm1 = (const float*)d_in[19]; const float* bm1 = (const float*)d_in[20];
  const float* Wm2 = (const float*)d_in[21]; const float* bm2 = (const float*)d_in[22];
  const int*   prev_values    = (const int*)d_in[23];
  const int*   next_values    = (const int*)d_in[24];
  const int*   window_indices = (const int*)d_in[25];
  const int*   indices        = (const int*)d_in[26];
  const float* prev_mask   = (const float*)d_in[27];
  const float* next_mask   = (const float*)d_in[28];
  const float* window_mask = (const float*)d_in[29];
  const float* max_depth   = (const float*)d_in[30];
  float* out = (float*)d_out;

  double* mdT = (double*)d_ws;                  // 32768 f64
  float* q  = (float*)(mdT + NROWS);
  float* k  = q  + (size_t)NROWS*DKD;
  float* v  = k  + (size_t)NROWS*DKD;
  float* cx = v  + (size_t)NROWS*DKD;
  int*   pvT  = (int*)(cx + (size_t)NROWS*DKD);
  int*   nvT  = pvT + NROWS;
  int*   idxT = nvT + NROWS;
  float* pmT  = (float*)(idxT + NROWS);
  float* nmT  = pmT + NROWS;
  float* w2t  = nmT + NROWS;                    // 3*6144 floats

  prep_kernel<<<NROWS/256, 256, 0, stream>>>(max_depth,
      prev_values, next_values, indices, prev_mask, next_mask,
      mdT, pvT, nvT, idxT, pmT, nmT);
  prep_w2t<<<(3*HID*DKD)/256, 256, 0, stream>>>(Wq2, Wk2, Wv2, w2t);
  qkv_kernel<<<3*(NROWS/BR), 256, 0, stream>>>(encoded,
      Wq1,bq1,bq2, Wk1,bk1,bk2, Wv1,bv1,bv2, w2t, q, k, v);
  attn_kernel<<<NROWS/4, 256, 0, stream>>>(q, k, v, role_emb, mdT,
      pvT, nvT, idxT, pmT, nmT, window_indices, window_mask, cx);
  heads_kernel<<<NROWS/BR16, 256, 0, stream>>>(encoded, cx, u,
      Wd1,bd1,Wd2,bd2, Wm1,bm1,Wm2,bm2, out);
}

// Round 14
// 167.882 us; speedup vs baseline: 1.6615x; 1.6615x over previous
//
#include <hip/hip_runtime.h>
#include <math.h>

#define VN 16
#define TN 2048
#define NROWS (VN*TN)   // 32768
#define DIN 64
#define HID 128
#define DKD 48
#define KNB 33
#define BR64 64
#define BR16 16
#define KPAD 52
#define XPAD 68   // s_x row: 64+4 floats = 272B (16B-aligned)
#define HPAD 66   // s_h row: 64+2 floats

// ---------------- Threefry-2x32, key = (0, 42) ----------------
__device__ __forceinline__ unsigned rotl32(unsigned x, int d){ return (x<<d)|(x>>(32-d)); }

__device__ __forceinline__ void tf2x32(unsigned c0, unsigned c1, unsigned& y0, unsigned& y1){
  const unsigned k0 = 0u, k1 = 42u;
  const unsigned k2 = k0 ^ k1 ^ 0x1BD11BDAu;
  unsigned x0 = c0, x1 = c1;
  x0 += k0; x1 += k1;
#define TF_R(r) { x0 += x1; x1 = rotl32(x1,(r)); x1 ^= x0; }
  TF_R(13) TF_R(15) TF_R(26) TF_R(6)   x0 += k1; x1 += k2 + 1u;
  TF_R(17) TF_R(29) TF_R(16) TF_R(24)  x0 += k2; x1 += k0 + 2u;
  TF_R(13) TF_R(15) TF_R(26) TF_R(6)   x0 += k0; x1 += k1 + 3u;
  TF_R(17) TF_R(29) TF_R(16) TF_R(24)  x0 += k1; x1 += k2 + 4u;
  TF_R(13) TF_R(15) TF_R(26) TF_R(6)   x0 += k2; x1 += k0 + 5u;
#undef TF_R
  y0 = x0; y1 = x1;
}

// exact f64 md for element n (partitionable 64-bit threefry stream, np-ref semantics)
__device__ __forceinline__ double md64_of(const float* __restrict__ max_depth, int n){
  unsigned y0, y1;
  tf2x32(0u, (unsigned)n, y0, y1);
  unsigned long long bits = (((unsigned long long)y0) << 32) | (unsigned long long)y1;
  unsigned long long fb = (bits >> 12) | 0x3FF0000000000000ull;   // [1,2)
  double f; __builtin_memcpy(&f, &fb, 8);
  f -= 1.0;
  return (double)max_depth[n] + f * (1.0/8192.0);
}

// ---------------- prep: md64 + metadata transposes [V][T] -> [T][16] ----------------
__global__ __launch_bounds__(256) void prep_kernel(const float* __restrict__ max_depth,
    const int* __restrict__ pv, const int* __restrict__ nv, const int* __restrict__ ind,
    const float* __restrict__ pm, const float* __restrict__ nm,
    double* __restrict__ mdT, int* __restrict__ pvT, int* __restrict__ nvT,
    int* __restrict__ idxT, float* __restrict__ pmT, float* __restrict__ nmT)
{
  int n = blockIdx.x*256 + threadIdx.x;
  int v = n >> 11, t = n & 2047;
  int o = t*VN + v;
  mdT[o]  = md64_of(max_depth, n);
  pvT[o]  = pv[n];
  nvT[o]  = nv[n];
  idxT[o] = ind[n];
  pmT[o]  = pm[n];
  nmT[o]  = nm[n];
}

// ---------------- q/k/v MLPs: BR=64, 8-row x 4-unit tile, streamed W ----------------
// 256 threads, mm split across grid (512 blocks per matrix).
// L1 per i: 2 broadcast LDS b128 + 1 coalesced global float4 -> 32 FMA (unroll 8).
__global__ __launch_bounds__(256) void qkv_kernel(const float* __restrict__ enc,
    const float* __restrict__ Wq1, const float* __restrict__ bq1,
    const float* __restrict__ Wq2, const float* __restrict__ bq2,
    const float* __restrict__ Wk1, const float* __restrict__ bk1,
    const float* __restrict__ Wk2, const float* __restrict__ bk2,
    const float* __restrict__ Wv1, const float* __restrict__ bv1,
    const float* __restrict__ Wv2, const float* __restrict__ bv2,
    float* __restrict__ qo, float* __restrict__ ko, float* __restrict__ vo)
{
  __shared__ __align__(16) float s_x[DIN][XPAD];     // 17.4 KB
  __shared__ __align__(16) float s_h[HID][HPAD];     // 33.8 KB
  int tid = threadIdx.x;
  int mm   = blockIdx.x / 512;
  int base = (blockIdx.x - mm*512) * BR64;

  const float *W1, *b1, *W2, *b2; float* outp;
  if (mm == 0){ W1=Wq1; b1=bq1; W2=Wq2; b2=bq2; outp=qo; }
  else if (mm == 1){ W1=Wk1; b1=bk1; W2=Wk2; b2=bk2; outp=ko; }
  else        { W1=Wv1; b1=bv1; W2=Wv2; b2=bv2; outp=vo; }

  for (int idx = tid; idx < BR64*DIN; idx += 256){
    int r = idx >> 6, c = idx & 63;
    s_x[c][r] = enc[(size_t)(base+r)*DIN + c];
  }
  __syncthreads();

  // layer 1: 8 rows x 4 units per thread
  const int u0 = (tid & 31) * 4;
  const int r0 = (tid >> 5) * 8;       // 8 groups x 8 rows = 64
  {
    float acc[8][4];
    float c0=b1[u0], c1=b1[u0+1], c2=b1[u0+2], c3=b1[u0+3];
    #pragma unroll
    for (int r=0;r<8;r++){ acc[r][0]=c0; acc[r][1]=c1; acc[r][2]=c2; acc[r][3]=c3; }
    #pragma unroll 8
    for (int i=0;i<DIN;i++){
      const float4 xa = *reinterpret_cast<const float4*>(&s_x[i][r0]);     // rows r0..r0+3 (broadcast)
      const float4 xb = *reinterpret_cast<const float4*>(&s_x[i][r0+4]);   // rows r0+4..r0+7
      const float4 wv = *reinterpret_cast<const float4*>(&W1[i*HID + u0]); // coalesced 512B/wave
      float xd[8] = {xa.x, xa.y, xa.z, xa.w, xb.x, xb.y, xb.z, xb.w};
      float wd[4] = {wv.x, wv.y, wv.z, wv.w};
      #pragma unroll
      for (int r=0;r<8;r++)
        #pragma unroll
        for (int j=0;j<4;j++)
          acc[r][j] = fmaf(xd[r], wd[j], acc[r][j]);
    }
    #pragma unroll
    for (int j=0;j<4;j++){
      float4 h0, h1;
      h0.x=fmaxf(acc[0][j],0.0f); h0.y=fmaxf(acc[1][j],0.0f);
      h0.z=fmaxf(acc[2][j],0.0f); h0.w=fmaxf(acc[3][j],0.0f);
      h1.x=fmaxf(acc[4][j],0.0f); h1.y=fmaxf(acc[5][j],0.0f);
      h1.z=fmaxf(acc[6][j],0.0f); h1.w=fmaxf(acc[7][j],0.0f);
      *reinterpret_cast<float4*>(&s_h[u0+j][r0])   = h0;
      *reinterpret_cast<float4*>(&s_h[u0+j][r0+4]) = h1;
    }
  }
  __syncthreads();

  // layer 2: 4 rows x 3 outputs per thread; per i: 1 LDS float4 + 3 coalesced scalar W2 -> 12 FMA
  const int uo0 = (tid & 15) * 3;
  const int rr0 = (tid >> 4) * 4;      // 16 groups x 4 rows = 64
  {
    float a[4][3];
    float c0=b2[uo0], c1=b2[uo0+1], c2=b2[uo0+2];
    #pragma unroll
    for (int r=0;r<4;r++){ a[r][0]=c0; a[r][1]=c1; a[r][2]=c2; }
    #pragma unroll 8
    for (int i=0;i<HID;i++){
      const float4 hv = *reinterpret_cast<const float4*>(&s_h[i][rr0]);
      float w0 = W2[i*DKD+uo0], w1 = W2[i*DKD+uo0+1], w2 = W2[i*DKD+uo0+2];
      float hd[4] = {hv.x, hv.y, hv.z, hv.w};
      #pragma unroll
      for (int r=0;r<4;r++){
        a[r][0]=fmaf(hd[r],w0,a[r][0]);
        a[r][1]=fmaf(hd[r],w1,a[r][1]);
        a[r][2]=fmaf(hd[r],w2,a[r][2]);
      }
    }
    #pragma unroll
    for (int r=0;r<4;r++){
      float* op = outp + (size_t)(base+rr0+r)*DKD;
      op[uo0]=a[r][0]; op[uo0+1]=a[r][1]; op[uo0+2]=a[r][2];
    }
  }
}

// ---------------- attention: direct K gather, LDS role, transposed metadata ----------------
__global__ __launch_bounds__(256) void attn_kernel(const float* __restrict__ qv,
    const float* __restrict__ kv, const float* __restrict__ vv,
    const float* __restrict__ role_emb, const double* __restrict__ mdT,
    const int* __restrict__ pvT, const int* __restrict__ nvT, const int* __restrict__ idxT,
    const float* __restrict__ pmT, const float* __restrict__ nmT,
    const int* __restrict__ window_indices, const float* __restrict__ window_mask,
    float* __restrict__ ctx_out)
{
  __shared__ __align__(16) float s_role[KNB][KPAD];   // 6.9 KB (block-uniform)
  __shared__ __align__(16) float s_q[4][DKD];
  __shared__ float s_p[4][KNB];
  __shared__ int   s_idx[4][KNB];
  int tid  = threadIdx.x;          // 256
  int wid  = tid >> 6;
  int lane = tid & 63;
  int n = blockIdx.x*4 + wid;
  int vrow = n >> 11;              // all 4 rows in block share vrow
  int t    = n & 2047;

  if (lane < DKD) s_q[wid][lane] = qv[(size_t)n*DKD + lane];

  // stage role rows (block-uniform: depend only on vrow)
  for (int idx = tid; idx < KNB*DKD; idx += 256){
    int j = idx / DKD, d = idx - j*DKD;
    int role = (j < 16) ? (vrow<<4)+j : ((j < 32) ? 256+(vrow<<4)+(j-16) : 512+vrow);
    s_role[j][d] = role_emb[(size_t)role*DKD + d];
  }
  __syncthreads();

  float sc = -INFINITY;
  if (lane < KNB){
    int gidx; bool valid;
    if (lane < 16){
      int o = t*VN + lane;
      gidx  = pvT[o];
      valid = (pmT[o] == 0.0f);
    } else if (lane < 32){
      int v2 = lane - 16, o = t*VN + v2;
      bool comp = mdT[t*VN + vrow] > mdT[o];   // exact f64 (np-ref semantics)
      gidx  = comp ? idxT[o] : nvT[o];
      valid = comp || (nmT[o] == 0.0f);
    } else {
      gidx  = window_indices[n];
      valid = (window_mask[n] == 0.0f);
    }
    s_idx[wid][lane] = gidx;
    // direct per-lane K gather: 3 independent float4 loads (HW-pipelined)
    const float4* kp = reinterpret_cast<const float4*>(kv + (size_t)gidx*DKD);
    float acc = 0.0f;
    #pragma unroll
    for (int d4 = 0; d4 < DKD/4; d4++){
      const float4 qq = *reinterpret_cast<const float4*>(&s_q[wid][4*d4]);
      const float4 rr = *reinterpret_cast<const float4*>(&s_role[lane][4*d4]);
      const float4 kk = kp[d4];
      acc = fmaf(qq.x, kk.x + rr.x, acc);
      acc = fmaf(qq.y, kk.y + rr.y, acc);
      acc = fmaf(qq.z, kk.z + rr.z, acc);
      acc = fmaf(qq.w, kk.w + rr.w, acc);
    }
    sc = acc / 6.928203230275509f;   // sqrt(48)
    if (!valid) sc = -1e9f;
  }
  float mx = sc;
  #pragma unroll
  for (int o=32;o>0;o>>=1) mx = fmaxf(mx, __shfl_xor(mx, o, 64));
  float e = (lane < KNB) ? expf(sc - mx) : 0.0f;
  float ssum = e;
  #pragma unroll
  for (int o=32;o>0;o>>=1) ssum += __shfl_xor(ssum, o, 64);
  if (lane < KNB) s_p[wid][lane] = e / ssum;

  if (lane < DKD){
    float c = 0.0f;
    #pragma unroll 8
    for (int j=0;j<KNB;j++)
      c = fmaf(s_p[wid][j], vv[(size_t)s_idx[wid][j]*DKD + lane], c);
    ctx_out[(size_t)n*DKD + lane] = c;
  }
}

// ---------------- heads: 16 rows/block, hidden in registers, shuffle-reduced layer2 ----------------
__device__ __forceinline__ double nlogp_d(double x, double mu, double ls){
  double sp = fmax(ls, 0.0) + log1p(exp(-fabs(ls)));
  double s = sp + 1e-3;
  double z = (x - mu) / s;
  return 0.5*z*z + log(s) + 0.9189385332046727417803297; // 0.5*log(2*pi)
}

__global__ __launch_bounds__(256) void heads_kernel(const float* __restrict__ enc,
    const float* __restrict__ ctx, const float* __restrict__ uu,
    const float* __restrict__ Wd1, const float* __restrict__ bd1,
    const float* __restrict__ Wd2, const float* __restrict__ bd2,
    const float* __restrict__ Wm1, const float* __restrict__ bm1,
    const float* __restrict__ Wm2, const float* __restrict__ bm2,
    float* __restrict__ out)
{
  __shared__ float s_x[DIN+DKD][BR16+2];   // [112][18] 8.06 KB
  __shared__ float s_o[BR16][4];
  int tid = threadIdx.x;     // 256
  int base = blockIdx.x * BR16;

  for (int idx = tid; idx < BR16*DIN; idx += 256){
    int r = idx >> 6, c = idx & 63;
    s_x[c][r] = enc[(size_t)(base+r)*DIN + c];
  }
  for (int idx = tid; idx < BR16*DKD; idx += 256){
    int r = idx / DKD, c = idx - r*DKD;
    s_x[DIN + c][r] = ctx[(size_t)(base+r)*DKD + c];
  }
  __syncthreads();

  const int u0 = (tid & 31) * 4;
  const int r0 = (tid >> 5) * 2;

  float pd[2][2] = {{0.f,0.f},{0.f,0.f}};
  float pm[2][2] = {{0.f,0.f},{0.f,0.f}};

  // dp: hidden 112->128 into regs, partial dot vs Wd2
  {
    float acc[2][4];
    float c0=bd1[u0], c1=bd1[u0+1], c2=bd1[u0+2], c3=bd1[u0+3];
    acc[0][0]=c0; acc[0][1]=c1; acc[0][2]=c2; acc[0][3]=c3;
    acc[1][0]=c0; acc[1][1]=c1; acc[1][2]=c2; acc[1][3]=c3;
    #pragma unroll 8
    for (int i=0;i<DIN+DKD;i++){
      const float2 xv = *reinterpret_cast<const float2*>(&s_x[i][r0]);
      const float4 wv = *reinterpret_cast<const float4*>(&Wd1[i*HID + u0]);
      acc[0][0]=fmaf(xv.x,wv.x,acc[0][0]); acc[0][1]=fmaf(xv.x,wv.y,acc[0][1]);
      acc[0][2]=fmaf(xv.x,wv.z,acc[0][2]); acc[0][3]=fmaf(xv.x,wv.w,acc[0][3]);
      acc[1][0]=fmaf(xv.y,wv.x,acc[1][0]); acc[1][1]=fmaf(xv.y,wv.y,acc[1][1]);
      acc[1][2]=fmaf(xv.y,wv.z,acc[1][2]); acc[1][3]=fmaf(xv.y,wv.w,acc[1][3]);
    }
    #pragma unroll
    for (int j=0;j<4;j++){
      const float2 w2 = *reinterpret_cast<const float2*>(&Wd2[(u0+j)*2]);
      float h0 = fmaxf(acc[0][j],0.0f), h1 = fmaxf(acc[1][j],0.0f);
      pd[0][0]=fmaf(h0,w2.x,pd[0][0]); pd[0][1]=fmaf(h0,w2.y,pd[0][1]);
      pd[1][0]=fmaf(h1,w2.x,pd[1][0]); pd[1][1]=fmaf(h1,w2.y,pd[1][1]);
    }
  }
  // mp: hidden 64->128 into regs, partial dot vs Wm2
  {
    float acc[2][4];
    float c0=bm1[u0], c1=bm1[u0+1], c2=bm1[u0+2], c3=bm1[u0+3];
    acc[0][0]=c0; acc[0][1]=c1; acc[0][2]=c2; acc[0][3]=c3;
    acc[1][0]=c0; acc[1][1]=c1; acc[1][2]=c2; acc[1][3]=c3;
    #pragma unroll 8
    for (int i=0;i<DIN;i++){
      const float2 xv = *reinterpret_cast<const float2*>(&s_x[i][r0]);
      const float4 wv = *reinterpret_cast<const float4*>(&Wm1[i*HID + u0]);
      acc[0][0]=fmaf(xv.x,wv.x,acc[0][0]); acc[0][1]=fmaf(xv.x,wv.y,acc[0][1]);
      acc[0][2]=fmaf(xv.x,wv.z,acc[0][2]); acc[0][3]=fmaf(xv.x,wv.w,acc[0][3]);
      acc[1][0]=fmaf(xv.y,wv.x,acc[1][0]); acc[1][1]=fmaf(xv.y,wv.y,acc[1][1]);
      acc[1][2]=fmaf(xv.y,wv.z,acc[1][2]); acc[1][3]=fmaf(xv.y,wv.w,acc[1][3]);
    }
    #pragma unroll
    for (int j=0;j<4;j++){
      const float2 w2 = *reinterpret_cast<const float2*>(&Wm2[(u0+j)*2]);
      float h0 = fmaxf(acc[0][j],0.0f), h1 = fmaxf(acc[1][j],0.0f);
      pm[0][0]=fmaf(h0,w2.x,pm[0][0]); pm[0][1]=fmaf(h0,w2.y,pm[0][1]);
      pm[1][0]=fmaf(h1,w2.x,pm[1][0]); pm[1][1]=fmaf(h1,w2.y,pm[1][1]);
    }
  }
  // tree-reduce the 8 partials over the 32 lanes sharing (r0, r0+1)
  #pragma unroll
  for (int o=1;o<=16;o<<=1){
    pd[0][0]+=__shfl_xor(pd[0][0],o,64); pd[0][1]+=__shfl_xor(pd[0][1],o,64);
    pd[1][0]+=__shfl_xor(pd[1][0],o,64); pd[1][1]+=__shfl_xor(pd[1][1],o,64);
    pm[0][0]+=__shfl_xor(pm[0][0],o,64); pm[0][1]+=__shfl_xor(pm[0][1],o,64);
    pm[1][0]+=__shfl_xor(pm[1][0],o,64); pm[1][1]+=__shfl_xor(pm[1][1],o,64);
  }
  if ((tid & 31) == 0){
    #pragma unroll
    for (int rr=0;rr<2;rr++){
      s_o[r0+rr][0] = pd[rr][0] + bd2[0];
      s_o[r0+rr][1] = pd[rr][1] + bd2[1];
      s_o[r0+rr][2] = pm[rr][0] + bm2[0];
      s_o[r0+rr][3] = pm[rr][1] + bm2[1];
    }
  }
  __syncthreads();

  if (tid < BR16){
    double x = (double)uu[base + tid];
    out[base + tid] = (float)(nlogp_d(x, (double)s_o[tid][0], (double)s_o[tid][1]) +
                              nlogp_d(x, (double)s_o[tid][2], (double)s_o[tid][3]));
  }
}

extern "C" void kernel_launch(void* const* d_in, const int* in_sizes, int n_in,
                              void* d_out, int out_size, void* d_ws, size_t ws_size,
                              hipStream_t stream) {
  const float* encoded = (const float*)d_in[0];
  const float* u       = (const float*)d_in[1];
  const float* Wq1 = (const float*)d_in[2];  const float* bq1 = (const float*)d_in[3];
  const float* Wq2 = (const float*)d_in[4];  const float* bq2 = (const float*)d_in[5];
  const float* Wk1 = (const float*)d_in[6];  const float* bk1 = (const float*)d_in[7];
  const float* Wk2 = (const float*)d_in[8];  const float* bk2 = (const float*)d_in[9];
  const float* Wv1 = (const float*)d_in[10]; const float* bv1 = (const float*)d_in[11];
  const float* Wv2 = (const float*)d_in[12]; const float* bv2 = (const float*)d_in[13];
  const float* role_emb = (const float*)d_in[14];
  const float* Wd1 = (const float*)d_in[15]; const float* bd1 = (const float*)d_in[16];
  const float* Wd2 = (const float*)d_in[17]; const float* bd2 = (const float*)d_in[18];
  const float* Wm1 = (const float*)d_in[19]; const float* bm1 = (const float*)d_in[20];
  const float* Wm2 = (const float*)d_in[21]; const float* bm2 = (const float*)d_in[22];
  const int*   prev_values    = (const int*)d_in[23];
  const int*   next_values    = (const int*)d_in[24];
  const int*   window_indices = (const int*)d_in[25];
  const int*   indices        = (const int*)d_in[26];
  const float* prev_mask   = (const float*)d_in[27];
  const float* next_mask   = (const float*)d_in[28];
  const float* window_mask = (const float*)d_in[29];
  const float* max_depth   = (const float*)d_in[30];
  float* out = (float*)d_out;

  double* mdT = (double*)d_ws;                  // 32768 f64
  float* q  = (float*)(mdT + NROWS);
  float* k  = q  + (size_t)NROWS*DKD;
  float* v  = k  + (size_t)NROWS*DKD;
  float* cx = v  + (size_t)NROWS*DKD;
  int*   pvT  = (int*)(cx + (size_t)NROWS*DKD);
  int*   nvT  = pvT + NROWS;
  int*   idxT = nvT + NROWS;
  float* pmT  = (float*)(idxT + NROWS);
  float* nmT  = pmT + NROWS;

  prep_kernel<<<NROWS/256, 256, 0, stream>>>(max_depth,
      prev_values, next_values, indices, prev_mask, next_mask,
      mdT, pvT, nvT, idxT, pmT, nmT);
  qkv_kernel<<<3*(NROWS/BR64), 256, 0, stream>>>(encoded,
      Wq1,bq1,Wq2,bq2, Wk1,bk1,Wk2,bk2, Wv1,bv1,Wv2,bv2, q, k, v);
  attn_kernel<<<NROWS/4, 256, 0, stream>>>(q, k, v, role_emb, mdT,
      pvT, nvT, idxT, pmT, nmT, window_indices, window_mask, cx);
  heads_kernel<<<NROWS/BR16, 256, 0, stream>>>(encoded, cx, u,
      Wd1,bd1,Wd2,bd2, Wm1,bm1,Wm2,bm2, out);
}

// Round 15
// 154.573 us; speedup vs baseline: 1.8045x; 1.0861x over previous
//
#include <hip/hip_runtime.h>
#include <math.h>

#define VN 16
#define TN 2048
#define NROWS (VN*TN)   // 32768
#define DIN 64
#define HID 128
#define DKD 48
#define KNB 33
#define BR64 64
#define BR16 16
#define KPAD 52
#define XPAD 68   // s_x row: 64+4 floats = 272B (16B-aligned)
#define HPAD 66   // s_h row: 64+2 floats

// ---------------- Threefry-2x32, key = (0, 42) ----------------
__device__ __forceinline__ unsigned rotl32(unsigned x, int d){ return (x<<d)|(x>>(32-d)); }

__device__ __forceinline__ void tf2x32(unsigned c0, unsigned c1, unsigned& y0, unsigned& y1){
  const unsigned k0 = 0u, k1 = 42u;
  const unsigned k2 = k0 ^ k1 ^ 0x1BD11BDAu;
  unsigned x0 = c0, x1 = c1;
  x0 += k0; x1 += k1;
#define TF_R(r) { x0 += x1; x1 = rotl32(x1,(r)); x1 ^= x0; }
  TF_R(13) TF_R(15) TF_R(26) TF_R(6)   x0 += k1; x1 += k2 + 1u;
  TF_R(17) TF_R(29) TF_R(16) TF_R(24)  x0 += k2; x1 += k0 + 2u;
  TF_R(13) TF_R(15) TF_R(26) TF_R(6)   x0 += k0; x1 += k1 + 3u;
  TF_R(17) TF_R(29) TF_R(16) TF_R(24)  x0 += k1; x1 += k2 + 4u;
  TF_R(13) TF_R(15) TF_R(26) TF_R(6)   x0 += k2; x1 += k0 + 5u;
#undef TF_R
  y0 = x0; y1 = x1;
}

// exact f64 md for element n (partitionable 64-bit threefry stream, np-ref semantics)
__device__ __forceinline__ double md64_of(const float* __restrict__ max_depth, int n){
  unsigned y0, y1;
  tf2x32(0u, (unsigned)n, y0, y1);
  unsigned long long bits = (((unsigned long long)y0) << 32) | (unsigned long long)y1;
  unsigned long long fb = (bits >> 12) | 0x3FF0000000000000ull;   // [1,2)
  double f; __builtin_memcpy(&f, &fb, 8);
  f -= 1.0;
  return (double)max_depth[n] + f * (1.0/8192.0);
}

// ---------------- prep: md64 + metadata transposes [V][T] -> [T][16] ----------------
__global__ __launch_bounds__(256) void prep_kernel(const float* __restrict__ max_depth,
    const int* __restrict__ pv, const int* __restrict__ nv,
    const float* __restrict__ pm, const float* __restrict__ nm,
    double* __restrict__ mdT, int* __restrict__ pvT, int* __restrict__ nvT,
    float* __restrict__ pmT, float* __restrict__ nmT)
{
  int n = blockIdx.x*256 + threadIdx.x;
  int v = n >> 11, t = n & 2047;
  int o = t*VN + v;
  mdT[o]  = md64_of(max_depth, n);
  pvT[o]  = pv[n];
  nvT[o]  = nv[n];
  pmT[o]  = pm[n];
  nmT[o]  = nm[n];
}

// ---------------- q/k/v MLPs: BR=64, 8-row x 4-unit tile, streamed W ----------------
__global__ __launch_bounds__(256) void qkv_kernel(const float* __restrict__ enc,
    const float* __restrict__ Wq1, const float* __restrict__ bq1,
    const float* __restrict__ Wq2, const float* __restrict__ bq2,
    const float* __restrict__ Wk1, const float* __restrict__ bk1,
    const float* __restrict__ Wk2, const float* __restrict__ bk2,
    const float* __restrict__ Wv1, const float* __restrict__ bv1,
    const float* __restrict__ Wv2, const float* __restrict__ bv2,
    float* __restrict__ qo, float* __restrict__ ko, float* __restrict__ vo)
{
  __shared__ __align__(16) float s_x[DIN][XPAD];     // 17.4 KB
  __shared__ __align__(16) float s_h[HID][HPAD];     // 33.8 KB
  int tid = threadIdx.x;
  int mm   = blockIdx.x / 512;
  int base = (blockIdx.x - mm*512) * BR64;

  const float *W1, *b1, *W2, *b2; float* outp;
  if (mm == 0){ W1=Wq1; b1=bq1; W2=Wq2; b2=bq2; outp=qo; }
  else if (mm == 1){ W1=Wk1; b1=bk1; W2=Wk2; b2=bk2; outp=ko; }
  else        { W1=Wv1; b1=bv1; W2=Wv2; b2=bv2; outp=vo; }

  for (int idx = tid; idx < BR64*DIN; idx += 256){
    int r = idx >> 6, c = idx & 63;
    s_x[c][r] = enc[(size_t)(base+r)*DIN + c];
  }
  __syncthreads();

  // layer 1: 8 rows x 4 units per thread
  const int u0 = (tid & 31) * 4;
  const int r0 = (tid >> 5) * 8;
  {
    float acc[8][4];
    float c0=b1[u0], c1=b1[u0+1], c2=b1[u0+2], c3=b1[u0+3];
    #pragma unroll
    for (int r=0;r<8;r++){ acc[r][0]=c0; acc[r][1]=c1; acc[r][2]=c2; acc[r][3]=c3; }
    #pragma unroll 8
    for (int i=0;i<DIN;i++){
      const float4 xa = *reinterpret_cast<const float4*>(&s_x[i][r0]);
      const float4 xb = *reinterpret_cast<const float4*>(&s_x[i][r0+4]);
      const float4 wv = *reinterpret_cast<const float4*>(&W1[i*HID + u0]);
      float xd[8] = {xa.x, xa.y, xa.z, xa.w, xb.x, xb.y, xb.z, xb.w};
      float wd[4] = {wv.x, wv.y, wv.z, wv.w};
      #pragma unroll
      for (int r=0;r<8;r++)
        #pragma unroll
        for (int j=0;j<4;j++)
          acc[r][j] = fmaf(xd[r], wd[j], acc[r][j]);
    }
    #pragma unroll
    for (int j=0;j<4;j++){
      float4 h0, h1;
      h0.x=fmaxf(acc[0][j],0.0f); h0.y=fmaxf(acc[1][j],0.0f);
      h0.z=fmaxf(acc[2][j],0.0f); h0.w=fmaxf(acc[3][j],0.0f);
      h1.x=fmaxf(acc[4][j],0.0f); h1.y=fmaxf(acc[5][j],0.0f);
      h1.z=fmaxf(acc[6][j],0.0f); h1.w=fmaxf(acc[7][j],0.0f);
      *reinterpret_cast<float4*>(&s_h[u0+j][r0])   = h0;
      *reinterpret_cast<float4*>(&s_h[u0+j][r0+4]) = h1;
    }
  }
  __syncthreads();

  // layer 2: 4 rows x 3 outputs per thread
  const int uo0 = (tid & 15) * 3;
  const int rr0 = (tid >> 4) * 4;
  {
    float a[4][3];
    float c0=b2[uo0], c1=b2[uo0+1], c2=b2[uo0+2];
    #pragma unroll
    for (int r=0;r<4;r++){ a[r][0]=c0; a[r][1]=c1; a[r][2]=c2; }
    #pragma unroll 8
    for (int i=0;i<HID;i++){
      const float4 hv = *reinterpret_cast<const float4*>(&s_h[i][rr0]);
      float w0 = W2[i*DKD+uo0], w1 = W2[i*DKD+uo0+1], w2 = W2[i*DKD+uo0+2];
      float hd[4] = {hv.x, hv.y, hv.z, hv.w};
      #pragma unroll
      for (int r=0;r<4;r++){
        a[r][0]=fmaf(hd[r],w0,a[r][0]);
        a[r][1]=fmaf(hd[r],w1,a[r][1]);
        a[r][2]=fmaf(hd[r],w2,a[r][2]);
      }
    }
    #pragma unroll
    for (int r=0;r<4;r++){
      float* op = outp + (size_t)(base+rr0+r)*DKD;
      op[uo0]=a[r][0]; op[uo0+1]=a[r][1]; op[uo0+2]=a[r][2];
    }
  }
}

// ---------------- attention: 2 rows/wave, SALU PV addressing, identity idx ----------------
__global__ __launch_bounds__(256) void attn_kernel(const float* __restrict__ qv,
    const float* __restrict__ kv, const float* __restrict__ vv,
    const float* __restrict__ role_emb, const double* __restrict__ mdT,
    const int* __restrict__ pvT, const int* __restrict__ nvT,
    const float* __restrict__ pmT, const float* __restrict__ nmT,
    const int* __restrict__ window_indices, const float* __restrict__ window_mask,
    float* __restrict__ ctx_out)
{
  __shared__ __align__(16) float s_role[KNB][KPAD];   // 6.9 KB (block-uniform)
  __shared__ __align__(16) float s_q[8][DKD];
  __shared__ float s_p[8][KNB];
  __shared__ int   s_idx[8][KNB];
  int tid  = threadIdx.x;          // 256 = 4 waves; block handles 8 rows (2 per wave)
  int wid  = tid >> 6;
  int lane = tid & 63;
  int nb = blockIdx.x*8;           // all 8 rows share vrow (8 | 2048)
  int n0 = nb + wid*2;             // this wave's rows: n0, n0+1
  int vrow = n0 >> 11;
  int t0   = n0 & 2047;

  for (int idx = tid; idx < 8*DKD; idx += 256){
    int r = idx / DKD, d = idx - r*DKD;
    s_q[r][d] = qv[(size_t)(nb+r)*DKD + d];
  }
  // stage role rows (block-uniform: depend only on vrow)
  for (int idx = tid; idx < KNB*DKD; idx += 256){
    int j = idx / DKD, d = idx - j*DKD;
    int role = (j < 16) ? (vrow<<4)+j : ((j < 32) ? 256+(vrow<<4)+(j-16) : 512+vrow);
    s_role[j][d] = role_emb[(size_t)role*DKD + d];
  }
  __syncthreads();

  float sc0 = -INFINITY, sc1 = -INFINITY;
  if (lane < KNB){
    int g0, g1; bool va0, va1;
    if (lane < 16){
      int o0 = t0*VN + lane, o1 = o0 + VN;
      g0 = pvT[o0];            g1 = pvT[o1];
      va0 = (pmT[o0] == 0.0f); va1 = (pmT[o1] == 0.0f);
    } else if (lane < 32){
      int v2 = lane - 16;
      int o0 = t0*VN + v2, o1 = o0 + VN;
      bool c0 = mdT[t0*VN + vrow]     > mdT[o0];   // exact f64 (np-ref semantics)
      bool c1 = mdT[(t0+1)*VN + vrow] > mdT[o1];
      g0 = c0 ? (v2*TN + t0)     : nvT[o0];        // indices input == flat identity
      g1 = c1 ? (v2*TN + t0 + 1) : nvT[o1];
      va0 = c0 || (nmT[o0] == 0.0f);
      va1 = c1 || (nmT[o1] == 0.0f);
    } else {
      g0 = window_indices[n0];   g1 = window_indices[n0+1];
      va0 = (window_mask[n0] == 0.0f); va1 = (window_mask[n0+1] == 0.0f);
    }
    s_idx[wid*2  ][lane] = g0;
    s_idx[wid*2+1][lane] = g1;
    const float4* kp0 = reinterpret_cast<const float4*>(kv + (size_t)g0*DKD);
    const float4* kp1 = reinterpret_cast<const float4*>(kv + (size_t)g1*DKD);
    float a0 = 0.0f, a1 = 0.0f;
    #pragma unroll
    for (int d4 = 0; d4 < DKD/4; d4++){
      const float4 rr = *reinterpret_cast<const float4*>(&s_role[lane][4*d4]);
      const float4 q0 = *reinterpret_cast<const float4*>(&s_q[wid*2  ][4*d4]);
      const float4 q1 = *reinterpret_cast<const float4*>(&s_q[wid*2+1][4*d4]);
      const float4 k0 = kp0[d4];
      const float4 k1 = kp1[d4];
      a0 = fmaf(q0.x, k0.x + rr.x, a0); a1 = fmaf(q1.x, k1.x + rr.x, a1);
      a0 = fmaf(q0.y, k0.y + rr.y, a0); a1 = fmaf(q1.y, k1.y + rr.y, a1);
      a0 = fmaf(q0.z, k0.z + rr.z, a0); a1 = fmaf(q1.z, k1.z + rr.z, a1);
      a0 = fmaf(q0.w, k0.w + rr.w, a0); a1 = fmaf(q1.w, k1.w + rr.w, a1);
    }
    sc0 = a0 / 6.928203230275509f;   // sqrt(48)
    sc1 = a1 / 6.928203230275509f;
    if (!va0) sc0 = -1e9f;
    if (!va1) sc1 = -1e9f;
  }
  float m0 = sc0, m1 = sc1;
  #pragma unroll
  for (int o=32;o>0;o>>=1){
    m0 = fmaxf(m0, __shfl_xor(m0, o, 64));
    m1 = fmaxf(m1, __shfl_xor(m1, o, 64));
  }
  float e0 = (lane < KNB) ? expf(sc0 - m0) : 0.0f;
  float e1 = (lane < KNB) ? expf(sc1 - m1) : 0.0f;
  float s0 = e0, s1 = e1;
  #pragma unroll
  for (int o=32;o>0;o>>=1){
    s0 += __shfl_xor(s0, o, 64);
    s1 += __shfl_xor(s1, o, 64);
  }
  if (lane < KNB){
    s_p[wid*2  ][lane] = e0 / s0;
    s_p[wid*2+1][lane] = e1 / s1;
  }

  if (lane < DKD){
    float c0 = 0.0f, c1 = 0.0f;
    #pragma unroll 8
    for (int j=0;j<KNB;j++){
      // wave-uniform index -> SGPR base, constant lane offset (SALU addressing)
      int i0 = __builtin_amdgcn_readfirstlane(s_idx[wid*2  ][j]);
      int i1 = __builtin_amdgcn_readfirstlane(s_idx[wid*2+1][j]);
      c0 = fmaf(s_p[wid*2  ][j], vv[(size_t)i0*DKD + lane], c0);
      c1 = fmaf(s_p[wid*2+1][j], vv[(size_t)i1*DKD + lane], c1);
    }
    ctx_out[(size_t)n0*DKD + lane]       = c0;
    ctx_out[(size_t)(n0+1)*DKD + lane]   = c1;
  }
}

// ---------------- heads: 16 rows/block, hidden in registers, shuffle-reduced layer2 ----------------
__device__ __forceinline__ double nlogp_d(double x, double mu, double ls){
  double sp = fmax(ls, 0.0) + log1p(exp(-fabs(ls)));
  double s = sp + 1e-3;
  double z = (x - mu) / s;
  return 0.5*z*z + log(s) + 0.9189385332046727417803297; // 0.5*log(2*pi)
}

__global__ __launch_bounds__(256) void heads_kernel(const float* __restrict__ enc,
    const float* __restrict__ ctx, const float* __restrict__ uu,
    const float* __restrict__ Wd1, const float* __restrict__ bd1,
    const float* __restrict__ Wd2, const float* __restrict__ bd2,
    const float* __restrict__ Wm1, const float* __restrict__ bm1,
    const float* __restrict__ Wm2, const float* __restrict__ bm2,
    float* __restrict__ out)
{
  __shared__ float s_x[DIN+DKD][BR16+2];   // [112][18] 8.06 KB
  __shared__ float s_o[BR16][4];
  int tid = threadIdx.x;     // 256
  int base = blockIdx.x * BR16;

  for (int idx = tid; idx < BR16*DIN; idx += 256){
    int r = idx >> 6, c = idx & 63;
    s_x[c][r] = enc[(size_t)(base+r)*DIN + c];
  }
  for (int idx = tid; idx < BR16*DKD; idx += 256){
    int r = idx / DKD, c = idx - r*DKD;
    s_x[DIN + c][r] = ctx[(size_t)(base+r)*DKD + c];
  }
  __syncthreads();

  const int u0 = (tid & 31) * 4;
  const int r0 = (tid >> 5) * 2;

  float pd[2][2] = {{0.f,0.f},{0.f,0.f}};
  float pm[2][2] = {{0.f,0.f},{0.f,0.f}};

  // dp: hidden 112->128 into regs, partial dot vs Wd2
  {
    float acc[2][4];
    float c0=bd1[u0], c1=bd1[u0+1], c2=bd1[u0+2], c3=bd1[u0+3];
    acc[0][0]=c0; acc[0][1]=c1; acc[0][2]=c2; acc[0][3]=c3;
    acc[1][0]=c0; acc[1][1]=c1; acc[1][2]=c2; acc[1][3]=c3;
    #pragma unroll 8
    for (int i=0;i<DIN+DKD;i++){
      const float2 xv = *reinterpret_cast<const float2*>(&s_x[i][r0]);
      const float4 wv = *reinterpret_cast<const float4*>(&Wd1[i*HID + u0]);
      acc[0][0]=fmaf(xv.x,wv.x,acc[0][0]); acc[0][1]=fmaf(xv.x,wv.y,acc[0][1]);
      acc[0][2]=fmaf(xv.x,wv.z,acc[0][2]); acc[0][3]=fmaf(xv.x,wv.w,acc[0][3]);
      acc[1][0]=fmaf(xv.y,wv.x,acc[1][0]); acc[1][1]=fmaf(xv.y,wv.y,acc[1][1]);
      acc[1][2]=fmaf(xv.y,wv.z,acc[1][2]); acc[1][3]=fmaf(xv.y,wv.w,acc[1][3]);
    }
    #pragma unroll
    for (int j=0;j<4;j++){
      const float2 w2 = *reinterpret_cast<const float2*>(&Wd2[(u0+j)*2]);
      float h0 = fmaxf(acc[0][j],0.0f), h1 = fmaxf(acc[1][j],0.0f);
      pd[0][0]=fmaf(h0,w2.x,pd[0][0]); pd[0][1]=fmaf(h0,w2.y,pd[0][1]);
      pd[1][0]=fmaf(h1,w2.x,pd[1][0]); pd[1][1]=fmaf(h1,w2.y,pd[1][1]);
    }
  }
  // mp: hidden 64->128 into regs, partial dot vs Wm2
  {
    float acc[2][4];
    float c0=bm1[u0], c1=bm1[u0+1], c2=bm1[u0+2], c3=bm1[u0+3];
    acc[0][0]=c0; acc[0][1]=c1; acc[0][2]=c2; acc[0][3]=c3;
    acc[1][0]=c0; acc[1][1]=c1; acc[1][2]=c2; acc[1][3]=c3;
    #pragma unroll 8
    for (int i=0;i<DIN;i++){
      const float2 xv = *reinterpret_cast<const float2*>(&s_x[i][r0]);
      const float4 wv = *reinterpret_cast<const float4*>(&Wm1[i*HID + u0]);
      acc[0][0]=fmaf(xv.x,wv.x,acc[0][0]); acc[0][1]=fmaf(xv.x,wv.y,acc[0][1]);
      acc[0][2]=fmaf(xv.x,wv.z,acc[0][2]); acc[0][3]=fmaf(xv.x,wv.w,acc[0][3]);
      acc[1][0]=fmaf(xv.y,wv.x,acc[1][0]); acc[1][1]=fmaf(xv.y,wv.y,acc[1][1]);
      acc[1][2]=fmaf(xv.y,wv.z,acc[1][2]); acc[1][3]=fmaf(xv.y,wv.w,acc[1][3]);
    }
    #pragma unroll
    for (int j=0;j<4;j++){
      const float2 w2 = *reinterpret_cast<const float2*>(&Wm2[(u0+j)*2]);
      float h0 = fmaxf(acc[0][j],0.0f), h1 = fmaxf(acc[1][j],0.0f);
      pm[0][0]=fmaf(h0,w2.x,pm[0][0]); pm[0][1]=fmaf(h0,w2.y,pm[0][1]);
      pm[1][0]=fmaf(h1,w2.x,pm[1][0]); pm[1][1]=fmaf(h1,w2.y,pm[1][1]);
    }
  }
  // tree-reduce the 8 partials over the 32 lanes sharing (r0, r0+1)
  #pragma unroll
  for (int o=1;o<=16;o<<=1){
    pd[0][0]+=__shfl_xor(pd[0][0],o,64); pd[0][1]+=__shfl_xor(pd[0][1],o,64);
    pd[1][0]+=__shfl_xor(pd[1][0],o,64); pd[1][1]+=__shfl_xor(pd[1][1],o,64);
    pm[0][0]+=__shfl_xor(pm[0][0],o,64); pm[0][1]+=__shfl_xor(pm[0][1],o,64);
    pm[1][0]+=__shfl_xor(pm[1][0],o,64); pm[1][1]+=__shfl_xor(pm[1][1],o,64);
  }
  if ((tid & 31) == 0){
    #pragma unroll
    for (int rr=0;rr<2;rr++){
      s_o[r0+rr][0] = pd[rr][0] + bd2[0];
      s_o[r0+rr][1] = pd[rr][1] + bd2[1];
      s_o[r0+rr][2] = pm[rr][0] + bm2[0];
      s_o[r0+rr][3] = pm[rr][1] + bm2[1];
    }
  }
  __syncthreads();

  if (tid < BR16){
    double x = (double)uu[base + tid];
    out[base + tid] = (float)(nlogp_d(x, (double)s_o[tid][0], (double)s_o[tid][1]) +
                              nlogp_d(x, (double)s_o[tid][2], (double)s_o[tid][3]));
  }
}

extern "C" void kernel_launch(void* const* d_in, const int* in_sizes, int n_in,
                              void* d_out, int out_size, void* d_ws, size_t ws_size,
                              hipStream_t stream) {
  const float* encoded = (const float*)d_in[0];
  const float* u       = (const float*)d_in[1];
  const float* Wq1 = (const float*)d_in[2];  const float* bq1 = (const float*)d_in[3];
  const float* Wq2 = (const float*)d_in[4];  const float* bq2 = (const float*)d_in[5];
  const float* Wk1 = (const float*)d_in[6];  const float* bk1 = (const float*)d_in[7];
  const float* Wk2 = (const float*)d_in[8];  const float* bk2 = (const float*)d_in[9];
  const float* Wv1 = (const float*)d_in[10]; const float* bv1 = (const float*)d_in[11];
  const float* Wv2 = (const float*)d_in[12]; const float* bv2 = (const float*)d_in[13];
  const float* role_emb = (const float*)d_in[14];
  const float* Wd1 = (const float*)d_in[15]; const float* bd1 = (const float*)d_in[16];
  const float* Wd2 = (const float*)d_in[17]; const float* bd2 = (const float*)d_in[18];
  const float* Wm1 = (const float*)d_in[19]; const float* bm1 = (const float*)d_in[20];
  const float* Wm2 = (const float*)d_in[21]; const float* bm2 = (const float*)d_in[22];
  const int*   prev_values    = (const int*)d_in[23];
  const int*   next_values    = (const int*)d_in[24];
  const int*   window_indices = (const int*)d_in[25];
  const float* prev_mask   = (const float*)d_in[27];
  const float* next_mask   = (const float*)d_in[28];
  const float* window_mask = (const float*)d_in[29];
  const float* max_depth   = (const float*)d_in[30];
  float* out = (float*)d_out;

  double* mdT = (double*)d_ws;                  // 32768 f64
  float* q  = (float*)(mdT + NROWS);
  float* k  = q  + (size_t)NROWS*DKD;
  float* v  = k  + (size_t)NROWS*DKD;
  float* cx = v  + (size_t)NROWS*DKD;
  int*   pvT  = (int*)(cx + (size_t)NROWS*DKD);
  int*   nvT  = pvT + NROWS;
  float* pmT  = (float*)(nvT + NROWS);
  float* nmT  = pmT + NROWS;

  prep_kernel<<<NROWS/256, 256, 0, stream>>>(max_depth,
      prev_values, next_values, prev_mask, next_mask,
      mdT, pvT, nvT, pmT, nmT);
  qkv_kernel<<<3*(NROWS/BR64), 256, 0, stream>>>(encoded,
      Wq1,bq1,Wq2,bq2, Wk1,bk1,Wk2,bk2, Wv1,bv1,Wv2,bv2, q, k, v);
  attn_kernel<<<NROWS/8, 256, 0, stream>>>(q, k, v, role_emb, mdT,
      pvT, nvT, pmT, nmT, window_indices, window_mask, cx);
  heads_kernel<<<NROWS/BR16, 256, 0, stream>>>(encoded, cx, u,
      Wd1,bd1,Wd2,bd2, Wm1,bm1,Wm2,bm2, out);
}